// Round 10
// baseline (53.750 us; speedup 1.0000x reference)
//
#include <hip/hip_runtime.h>
#include <math.h>

// TranscendentalMetaRL — round 10: 3 kernels.
//
// Math (unchanged since R6, passing at the fp32 comparison floor):
//   attended[b,h,q,:] == vbar[b,h]  =>  y = LayerNorm(x + c_b),
//   c_b = ((xbar_b@Weff_b^T + beff_b)@Wv^T + bv)@Wo^T + bo,
//   Weff = 0.2*sum_l cl_l consW_l, beff = 0.2*sum_l cl_l consb_l.
//   Q/K/attention/gate/phase all dead. fp32 throughout.
//
// R9 lesson: K2's serial part-reduce was latency-bound (not BW) — ILP depth
// is the lever. R10: 8-deep reduce ILP; cb folded into K2 via linearity
//   cb = sum_s Wo@pc_s + (Wo@bv + bo),  pc_s = Wv[:,slice_s]@pl_s
// (per-block partial matvec + atomicAdd, designated block adds constants).

namespace {

constexpr int B = 2, S = 2048, E = 512, H = 8, L = 5;
constexpr float LN_EPS = 1e-5f;
constexpr int NPART = 64;   // x column-sum chunks per batch (32 rows each)

// ---------------- K1: partial column sums; also cb := 0 (atomic base)
// Thread t owns columns 2t, 2t+1 (float2-coalesced), 4-deep ILP.
__global__ __launch_bounds__(256) void colsum_kernel(
    const float* __restrict__ x, float* __restrict__ part,
    float* __restrict__ cb)
{
  const int bid = blockIdx.x;          // B*NPART
  const int b = bid >> 6, j = bid & (NPART - 1);
  const int t = threadIdx.x;
  const float2* xp = reinterpret_cast<const float2*>(
      x + ((size_t)b * S + (size_t)j * (S / NPART)) * E);
  float2 a0 = {0.f, 0.f}, a1 = {0.f, 0.f}, a2 = {0.f, 0.f}, a3 = {0.f, 0.f};
#pragma unroll
  for (int r = 0; r < S / NPART; r += 4) {
    float2 v0 = xp[(size_t)(r + 0) * 256 + t];
    float2 v1 = xp[(size_t)(r + 1) * 256 + t];
    float2 v2 = xp[(size_t)(r + 2) * 256 + t];
    float2 v3 = xp[(size_t)(r + 3) * 256 + t];
    a0.x += v0.x; a0.y += v0.y;
    a1.x += v1.x; a1.y += v1.y;
    a2.x += v2.x; a2.y += v2.y;
    a3.x += v3.x; a3.y += v3.y;
  }
  float2 s = {a0.x + a1.x + a2.x + a3.x, a0.y + a1.y + a2.y + a3.y};
  reinterpret_cast<float2*>(part)[((size_t)b * NPART + j) * 256 + t] = s;
  if (bid == 0) {  // zero the cb atomic accumulator (fresh every call)
#pragma unroll
    for (int k = 0; k < 4; ++k) cb[k * 256 + t] = 0.f;
  }
}

// ---------------- K2: xbar + pooled slice + partial cvec + partial cb atomics
// grid = B*32 blocks; block owns o-slice [o0, o0+16).
__global__ __launch_bounds__(256) void pooled_kernel(
    const float* __restrict__ part, const float* __restrict__ cl,
    const float* __restrict__ consW, const float* __restrict__ consb,
    const float* __restrict__ Wv, const float* __restrict__ bv,
    const float* __restrict__ Wo, const float* __restrict__ bo,
    float* __restrict__ cb)
{
  __shared__ float xb[E];
  __shared__ float pl[16];
  __shared__ float pc[E];
  const int bid = blockIdx.x;
  const int b = bid >> 5, o0 = (bid & 31) * 16;
  const bool lead = (bid & 31) == 0;  // adds the bv/bo constant terms
  const int t = threadIdx.x;

  {  // A: xbar — reduce part (L2-resident), 8-deep ILP
    const float2* pp = reinterpret_cast<const float2*>(part) +
                       (size_t)b * NPART * 256;
    float2 a[8];
#pragma unroll
    for (int k = 0; k < 8; ++k) a[k] = {0.f, 0.f};
#pragma unroll
    for (int j = 0; j < NPART; j += 8) {
#pragma unroll
      for (int k = 0; k < 8; ++k) {
        float2 v = pp[(size_t)(j + k) * 256 + t];
        a[k].x += v.x; a[k].y += v.y;
      }
    }
    float sx = 0.f, sy = 0.f;
#pragma unroll
    for (int k = 0; k < 8; ++k) { sx += a[k].x; sy += a[k].y; }
    xb[2 * t]     = sx * (1.f / S);
    xb[2 * t + 1] = sy * (1.f / S);
  }
  __syncthreads();

  {  // B: pooled[o0 + (t>>4)] — 16 lanes per o, 32-wide i-chunks
    const int o = o0 + (t >> 4), chunk = t & 15, i0 = chunk * 32;
    float acc = 0.f;
#pragma unroll
    for (int l = 0; l < L; ++l) {
      const float* wr = &consW[((size_t)l * E + o) * E + i0];
      float d = 0.f;
#pragma unroll
      for (int i = 0; i < 32; i += 4) {
        float4 w = *reinterpret_cast<const float4*>(&wr[i]);
        d += w.x * xb[i0 + i] + w.y * xb[i0 + i + 1] +
             w.z * xb[i0 + i + 2] + w.w * xb[i0 + i + 3];
      }
      acc += cl[b * H + l] * d;
    }
    acc += __shfl_xor(acc, 1);
    acc += __shfl_xor(acc, 2);
    acc += __shfl_xor(acc, 4);
    acc += __shfl_xor(acc, 8);
    if (chunk == 0) {
      float bs = 0.f;
#pragma unroll
      for (int l = 0; l < L; ++l) bs += cl[b * H + l] * consb[l * E + o];
      pl[o - o0] = 0.2f * (acc + bs);
    }
  }
  __syncthreads();

  {  // C: pc[d] = Wv[d, slice] @ pl  (+ bv on the lead block)
#pragma unroll
    for (int k = 0; k < 2; ++k) {
      const int d = k * 256 + t;
      const float* wr = &Wv[(size_t)d * E + o0];
      float s = 0.f;
#pragma unroll
      for (int j = 0; j < 16; j += 4) {
        float4 w = *reinterpret_cast<const float4*>(&wr[j]);
        s += w.x * pl[j] + w.y * pl[j + 1] + w.z * pl[j + 2] + w.w * pl[j + 3];
      }
      pc[d] = lead ? s + bv[d] : s;
    }
  }
  __syncthreads();

  {  // D: cb[d2] += Wo[d2,:] @ pc  (+ bo on the lead block)
#pragma unroll
    for (int k = 0; k < 2; ++k) {
      const int d2 = k * 256 + t;
      const float* wr = &Wo[(size_t)d2 * E];
      float acc = 0.f;
#pragma unroll 4
      for (int i = 0; i < E; i += 4) {
        float4 w = *reinterpret_cast<const float4*>(&wr[i]);
        acc += w.x * pc[i] + w.y * pc[i + 1] + w.z * pc[i + 2] + w.w * pc[i + 3];
      }
      if (lead) acc += bo[d2];
      atomicAdd(&cb[b * E + d2], acc);
    }
  }
}

// ---------------- K3: out = LN(x + c_b)
__global__ __launch_bounds__(256) void ln_kernel(
    const float* __restrict__ x, const float* __restrict__ cb,
    const float* __restrict__ g, const float* __restrict__ bta,
    float* __restrict__ out)
{
  const int w = threadIdx.x >> 6, lane = threadIdx.x & 63;
  const size_t row = (size_t)blockIdx.x * 4 + w;
  const int b = (int)(row >> 11);  // S = 2048
  const float* y = x + row * E;
  const float* cc = cb + b * E;
  const int d0 = lane * 8;
  float4 a = *reinterpret_cast<const float4*>(&y[d0]);
  float4 c = *reinterpret_cast<const float4*>(&y[d0 + 4]);
  float4 ca = *reinterpret_cast<const float4*>(&cc[d0]);
  float4 cz = *reinterpret_cast<const float4*>(&cc[d0 + 4]);
  a.x += ca.x; a.y += ca.y; a.z += ca.z; a.w += ca.w;
  c.x += cz.x; c.y += cz.y; c.z += cz.z; c.w += cz.w;
  float s = a.x + a.y + a.z + a.w + c.x + c.y + c.z + c.w;
  float q = a.x * a.x + a.y * a.y + a.z * a.z + a.w * a.w +
            c.x * c.x + c.y * c.y + c.z * c.z + c.w * c.w;
#pragma unroll
  for (int o = 32; o > 0; o >>= 1) {
    s += __shfl_xor(s, o);
    q += __shfl_xor(q, o);
  }
  const float mu = s * (1.f / E);
  const float var = q * (1.f / E) - mu * mu;
  const float rstd = rsqrtf(var + LN_EPS);
  float4 g0 = *reinterpret_cast<const float4*>(&g[d0]);
  float4 g1 = *reinterpret_cast<const float4*>(&g[d0 + 4]);
  float4 b0 = *reinterpret_cast<const float4*>(&bta[d0]);
  float4 b1 = *reinterpret_cast<const float4*>(&bta[d0 + 4]);
  float4 o0, o1;
  o0.x = (a.x - mu) * rstd * g0.x + b0.x;
  o0.y = (a.y - mu) * rstd * g0.y + b0.y;
  o0.z = (a.z - mu) * rstd * g0.z + b0.z;
  o0.w = (a.w - mu) * rstd * g0.w + b0.w;
  o1.x = (c.x - mu) * rstd * g1.x + b1.x;
  o1.y = (c.y - mu) * rstd * g1.y + b1.y;
  o1.z = (c.z - mu) * rstd * g1.z + b1.z;
  o1.w = (c.w - mu) * rstd * g1.w + b1.w;
  *reinterpret_cast<float4*>(&out[row * E + d0]) = o0;
  *reinterpret_cast<float4*>(&out[row * E + d0 + 4]) = o1;
}

}  // namespace

extern "C" void kernel_launch(void* const* d_in, const int* in_sizes, int n_in,
                              void* d_out, int out_size, void* d_ws, size_t ws_size,
                              hipStream_t stream) {
  const float* x     = (const float*)d_in[0];
  const float* cl    = (const float*)d_in[1];
  const float* consW = (const float*)d_in[2];
  const float* consb = (const float*)d_in[3];
  // dead: d_in[4] freq_W, [5] freq_b, [6] Wq, [7] bq, [8] Wk, [9] bk,
  //       [14] gate, [15] phi_phase  (attention output is constant over q)
  const float* Wv  = (const float*)d_in[10];
  const float* bv  = (const float*)d_in[11];
  const float* Wo  = (const float*)d_in[12];
  const float* bo  = (const float*)d_in[13];
  const float* lng = (const float*)d_in[16];
  const float* lnb = (const float*)d_in[17];

  float* ws = (float*)d_ws;
  float* part = ws;                             // B*NPART*E
  float* cb   = part + (size_t)B * NPART * E;   // B*E (atomic accumulator)
  float* outp = (float*)d_out;

  hipLaunchKernelGGL(colsum_kernel, dim3(B * NPART), dim3(256), 0, stream,
                     x, part, cb);
  hipLaunchKernelGGL(pooled_kernel, dim3(B * 32), dim3(256), 0, stream,
                     part, cl, consW, consb, Wv, bv, Wo, bo, cb);
  hipLaunchKernelGGL(ln_kernel, dim3((B * S) / 4), dim3(256), 0, stream,
                     x, cb, lng, lnb, outp);
}

// Round 11
// 27.906 us; speedup vs baseline: 1.9261x; 1.9261x over previous
//
#include <hip/hip_runtime.h>
#include <math.h>

// TranscendentalMetaRL — round 11: R9 (proven 27.9us) + 8-deep reduce ILP.
//
// Math (unchanged since R6, passing at the fp32 comparison floor):
//   attended[b,h,q,:] == vbar[b,h]  =>  y = LayerNorm(x + c_b),
//   c_b = ((xbar_b@Weff_b^T + beff_b)@Wv^T + bv)@Wo^T + bo,
//   Weff = 0.2*sum_l cl_l consW_l, beff = 0.2*sum_l cl_l consb_l.
//   Q/K/attention/gate/phase all dead. fp32 throughout.
//
// R10 lesson: folding the Wo matvec into the 64-block pooled kernel exposed
// uncoalesced row-per-thread loads at 1 wave/SIMD occupancy -> 45us. Keep
// the cb matvec as its own kernel (8 threads/row, latency hidden by
// neighboring dispatches). This round = R9 + 8-deep ILP in K2's reduce.

namespace {

constexpr int B = 2, S = 2048, E = 512, H = 8, L = 5;
constexpr float LN_EPS = 1e-5f;
constexpr int NPART = 64;   // x column-sum chunks per batch (32 rows each)

// ---------------- K1: partial column sums; also cvec := bv (atomic base)
// Thread t owns columns 2t, 2t+1 (float2-coalesced), 4-deep ILP.
__global__ __launch_bounds__(256) void colsum_kernel(
    const float* __restrict__ x, const float* __restrict__ bv,
    float* __restrict__ part, float* __restrict__ cvec)
{
  const int bid = blockIdx.x;          // B*NPART
  const int b = bid >> 6, j = bid & (NPART - 1);
  const int t = threadIdx.x;
  const float2* xp = reinterpret_cast<const float2*>(
      x + ((size_t)b * S + (size_t)j * (S / NPART)) * E);
  float2 a0 = {0.f, 0.f}, a1 = {0.f, 0.f}, a2 = {0.f, 0.f}, a3 = {0.f, 0.f};
#pragma unroll
  for (int r = 0; r < S / NPART; r += 4) {
    float2 v0 = xp[(size_t)(r + 0) * 256 + t];
    float2 v1 = xp[(size_t)(r + 1) * 256 + t];
    float2 v2 = xp[(size_t)(r + 2) * 256 + t];
    float2 v3 = xp[(size_t)(r + 3) * 256 + t];
    a0.x += v0.x; a0.y += v0.y;
    a1.x += v1.x; a1.y += v1.y;
    a2.x += v2.x; a2.y += v2.y;
    a3.x += v3.x; a3.y += v3.y;
  }
  float2 s = {a0.x + a1.x + a2.x + a3.x, a0.y + a1.y + a2.y + a3.y};
  reinterpret_cast<float2*>(part)[((size_t)b * NPART + j) * 256 + t] = s;
  if (bid == 0) {  // init cvec accumulator = bv (fresh every call)
#pragma unroll
    for (int k = 0; k < 4; ++k) {
      int idx = k * 256 + t;               // 0..1023 = [B][E]
      cvec[idx] = bv[idx & (E - 1)];
    }
  }
}

// ---------------- K2: xbar + pooled slice + cvec atomic partials
// grid = B*32 blocks; block owns o-slice [o0, o0+16).
__global__ __launch_bounds__(256) void pooled_kernel(
    const float* __restrict__ part, const float* __restrict__ cl,
    const float* __restrict__ consW, const float* __restrict__ consb,
    const float* __restrict__ Wv, float* __restrict__ cvec)
{
  __shared__ float xb[E];
  __shared__ float pl[16];
  const int bid = blockIdx.x;
  const int b = bid >> 5, o0 = (bid & 31) * 16;
  const int t = threadIdx.x;

  {  // xbar — reduce part (L2-resident, 128KB), 8-deep ILP
    const float2* pp = reinterpret_cast<const float2*>(part) +
                       (size_t)b * NPART * 256;
    float2 a[8];
#pragma unroll
    for (int k = 0; k < 8; ++k) a[k] = {0.f, 0.f};
#pragma unroll
    for (int j = 0; j < NPART; j += 8) {
#pragma unroll
      for (int k = 0; k < 8; ++k) {
        float2 v = pp[(size_t)(j + k) * 256 + t];
        a[k].x += v.x; a[k].y += v.y;
      }
    }
    float sx = 0.f, sy = 0.f;
#pragma unroll
    for (int k = 0; k < 8; ++k) { sx += a[k].x; sy += a[k].y; }
    xb[2 * t]     = sx * (1.f / S);
    xb[2 * t + 1] = sy * (1.f / S);
  }
  __syncthreads();

  {  // pooled[o0 + (t>>4)] — 16 lanes per o, 32-wide i-chunks
    const int o = o0 + (t >> 4), chunk = t & 15, i0 = chunk * 32;
    float acc = 0.f;
#pragma unroll
    for (int l = 0; l < L; ++l) {
      const float* wr = &consW[((size_t)l * E + o) * E + i0];
      float d = 0.f;
#pragma unroll
      for (int i = 0; i < 32; i += 4) {
        float4 w = *reinterpret_cast<const float4*>(&wr[i]);
        d += w.x * xb[i0 + i] + w.y * xb[i0 + i + 1] +
             w.z * xb[i0 + i + 2] + w.w * xb[i0 + i + 3];
      }
      acc += cl[b * H + l] * d;
    }
    acc += __shfl_xor(acc, 1);
    acc += __shfl_xor(acc, 2);
    acc += __shfl_xor(acc, 4);
    acc += __shfl_xor(acc, 8);
    if (chunk == 0) {
      float bs = 0.f;
#pragma unroll
      for (int l = 0; l < L; ++l) bs += cl[b * H + l] * consb[l * E + o];
      pl[o - o0] = 0.2f * (acc + bs);
    }
  }
  __syncthreads();

  {  // cvec[d] += sum_{o in slice} Wv[d,o] * pl[o-o0]; 2 d's per thread
#pragma unroll
    for (int k = 0; k < 2; ++k) {
      const int d = k * 256 + t;
      const float* wr = &Wv[(size_t)d * E + o0];
      float s = 0.f;
#pragma unroll
      for (int j = 0; j < 16; j += 4) {
        float4 w = *reinterpret_cast<const float4*>(&wr[j]);
        s += w.x * pl[j] + w.y * pl[j + 1] + w.z * pl[j + 2] + w.w * pl[j + 3];
      }
      atomicAdd(&cvec[b * E + d], s);
    }
  }
}

// ---------------- K3: cb = cvec@Wo^T + bo  (B*16 blocks, 32 rows each)
__global__ __launch_bounds__(256) void cb_kernel(
    const float* __restrict__ cvec, const float* __restrict__ Wo,
    const float* __restrict__ bo, float* __restrict__ cb)
{
  __shared__ float vv[E];
  const int b = blockIdx.x >> 4, d0 = (blockIdx.x & 15) * 32;
  const int t = threadIdx.x;
  vv[t] = cvec[b * E + t];
  vv[t + 256] = cvec[b * E + t + 256];
  __syncthreads();
  const int d = d0 + (t >> 3), chunk = t & 7, i0 = chunk * 64;
  const float* wr = &Wo[(size_t)d * E + i0];
  float acc = 0.f;
#pragma unroll
  for (int i = 0; i < 64; i += 4) {
    float4 w = *reinterpret_cast<const float4*>(&wr[i]);
    acc += w.x * vv[i0 + i] + w.y * vv[i0 + i + 1] +
           w.z * vv[i0 + i + 2] + w.w * vv[i0 + i + 3];
  }
  acc += __shfl_xor(acc, 1);
  acc += __shfl_xor(acc, 2);
  acc += __shfl_xor(acc, 4);
  if (chunk == 0) cb[b * E + d] = acc + bo[d];
}

// ---------------- K4: out = LN(x + c_b)
__global__ __launch_bounds__(256) void ln_kernel(
    const float* __restrict__ x, const float* __restrict__ cb,
    const float* __restrict__ g, const float* __restrict__ bta,
    float* __restrict__ out)
{
  const int w = threadIdx.x >> 6, lane = threadIdx.x & 63;
  const size_t row = (size_t)blockIdx.x * 4 + w;
  const int b = (int)(row >> 11);  // S = 2048
  const float* y = x + row * E;
  const float* cc = cb + b * E;
  const int d0 = lane * 8;
  float4 a = *reinterpret_cast<const float4*>(&y[d0]);
  float4 c = *reinterpret_cast<const float4*>(&y[d0 + 4]);
  float4 ca = *reinterpret_cast<const float4*>(&cc[d0]);
  float4 cz = *reinterpret_cast<const float4*>(&cc[d0 + 4]);
  a.x += ca.x; a.y += ca.y; a.z += ca.z; a.w += ca.w;
  c.x += cz.x; c.y += cz.y; c.z += cz.z; c.w += cz.w;
  float s = a.x + a.y + a.z + a.w + c.x + c.y + c.z + c.w;
  float q = a.x * a.x + a.y * a.y + a.z * a.z + a.w * a.w +
            c.x * c.x + c.y * c.y + c.z * c.z + c.w * c.w;
#pragma unroll
  for (int o = 32; o > 0; o >>= 1) {
    s += __shfl_xor(s, o);
    q += __shfl_xor(q, o);
  }
  const float mu = s * (1.f / E);
  const float var = q * (1.f / E) - mu * mu;
  const float rstd = rsqrtf(var + LN_EPS);
  float4 g0 = *reinterpret_cast<const float4*>(&g[d0]);
  float4 g1 = *reinterpret_cast<const float4*>(&g[d0 + 4]);
  float4 b0 = *reinterpret_cast<const float4*>(&bta[d0]);
  float4 b1 = *reinterpret_cast<const float4*>(&bta[d0 + 4]);
  float4 o0, o1;
  o0.x = (a.x - mu) * rstd * g0.x + b0.x;
  o0.y = (a.y - mu) * rstd * g0.y + b0.y;
  o0.z = (a.z - mu) * rstd * g0.z + b0.z;
  o0.w = (a.w - mu) * rstd * g0.w + b0.w;
  o1.x = (c.x - mu) * rstd * g1.x + b1.x;
  o1.y = (c.y - mu) * rstd * g1.y + b1.y;
  o1.z = (c.z - mu) * rstd * g1.z + b1.z;
  o1.w = (c.w - mu) * rstd * g1.w + b1.w;
  *reinterpret_cast<float4*>(&out[row * E + d0]) = o0;
  *reinterpret_cast<float4*>(&out[row * E + d0 + 4]) = o1;
}

}  // namespace

extern "C" void kernel_launch(void* const* d_in, const int* in_sizes, int n_in,
                              void* d_out, int out_size, void* d_ws, size_t ws_size,
                              hipStream_t stream) {
  const float* x     = (const float*)d_in[0];
  const float* cl    = (const float*)d_in[1];
  const float* consW = (const float*)d_in[2];
  const float* consb = (const float*)d_in[3];
  // dead: d_in[4] freq_W, [5] freq_b, [6] Wq, [7] bq, [8] Wk, [9] bk,
  //       [14] gate, [15] phi_phase  (attention output is constant over q)
  const float* Wv  = (const float*)d_in[10];
  const float* bv  = (const float*)d_in[11];
  const float* Wo  = (const float*)d_in[12];
  const float* bo  = (const float*)d_in[13];
  const float* lng = (const float*)d_in[16];
  const float* lnb = (const float*)d_in[17];

  float* ws = (float*)d_ws;
  float* part = ws;                             // B*NPART*E
  float* cvec = part + (size_t)B * NPART * E;   // B*E (atomic accumulator)
  float* cb   = cvec + B * E;                   // B*E
  float* outp = (float*)d_out;

  hipLaunchKernelGGL(colsum_kernel, dim3(B * NPART), dim3(256), 0, stream,
                     x, bv, part, cvec);
  hipLaunchKernelGGL(pooled_kernel, dim3(B * 32), dim3(256), 0, stream,
                     part, cl, consW, consb, Wv, cvec);
  hipLaunchKernelGGL(cb_kernel, dim3(B * 16), dim3(256), 0, stream,
                     cvec, Wo, bo, cb);
  hipLaunchKernelGGL(ln_kernel, dim3((B * S) / 4), dim3(256), 0, stream,
                     x, cb, lng, lnb, outp);
}